// Round 11
// baseline (984.642 us; speedup 1.0000x reference)
//
#include <hip/hip_runtime.h>
#include <hip/hip_bf16.h>

#define TSTEPS 2048
#define NB 64
#define DH 256
#define NBDH (NB * DH)

typedef __attribute__((ext_vector_type(8))) short short8;
typedef __attribute__((ext_vector_type(4))) float f32x4;
typedef __attribute__((ext_vector_type(4))) int i32x4;

#define WSCALE 2032.0f
#define HSCALE 127.0f
#define INVSC (1.0f / (2032.0f * 127.0f))

__device__ __forceinline__ unsigned short f2bf(float f) {
  union { float f; unsigned u; } v; v.f = f;
  unsigned u = v.u;
  u += 0x7FFFu + ((u >> 16) & 1u);   // round-to-nearest-even
  return (unsigned short)(u >> 16);
}

__device__ __forceinline__ float fast_tanh(float x) {
  // tanh(x) = 1 - 2/(e^{2x}+1); saturates correctly at +/-1
  float e = __builtin_amdgcn_exp2f(x * 2.885390081777927f);  // e^{2x}
  return 1.0f - 2.0f * __builtin_amdgcn_rcpf(e + 1.0f);
}

// klin 4-way pairing permutation (period-3 rotation within 64-col blocks):
// stored position p holds original column p2c(p). Used consistently by
// cvt_w (W_hid, W_out k-dim), scan h-layout, h0 ingest, hlast un-permute.
__device__ __forceinline__ int p2c(int p) {
  int q = p & 63;
  return (p & ~63) | ((q & 3) << 4) | (q >> 2);
}

// ---- kernel 0: weights. W_in -> bf16 (unpermuted); W_out -> bf16 k-permuted
// (klin); W_hid -> int8 k-permuted (klin), scale 2032.
__global__ void cvt_w(const float* __restrict__ win, const float* __restrict__ whid,
                      const float* __restrict__ wout, unsigned short* __restrict__ wbf,
                      char* __restrict__ wq) {
  int i = blockIdx.x * 256 + threadIdx.x;  // 0 .. 3*65536-1
  int mat = i >> 16, idx = i & 65535;
  int n = idx >> 8, klin = idx & 255;
  if (mat == 0) {
    wbf[idx] = f2bf(win[idx]);
  } else if (mat == 1) {
    wbf[65536 + idx] = f2bf(wout[n * 256 + p2c(klin)]);
  } else {
    float v = whid[n * 256 + p2c(klin)] * WSCALE;
    int q = (int)__builtin_rintf(fminf(fmaxf(v, -127.f), 127.f));
    wq[idx] = (char)q;
  }
}

// ---- kernel 1: input GEMM  xp[M,256] = x[M,256] @ W_in^T  (f32 out)
__global__ __launch_bounds__(256) void gemm_in(
    const float* __restrict__ x, const unsigned short* __restrict__ Wbf,
    float* __restrict__ Cout) {
  const int w = threadIdx.x >> 6, l = threadIdx.x & 63;
  const int m16 = l & 15, kg = l >> 4;
  const long tile0 = ((long)blockIdx.x * 4 + w) * 2;

  short8 afr[2][8];
  for (int ti = 0; ti < 2; ++ti) {
    const float* ar = x + ((tile0 + ti) * 16 + m16) * 256 + kg * 8;
    for (int ks = 0; ks < 8; ++ks) {
      float4 f0 = *(const float4*)(ar + ks * 32);
      float4 f1 = *(const float4*)(ar + ks * 32 + 4);
      short8 s;
      s[0] = (short)f2bf(f0.x); s[1] = (short)f2bf(f0.y);
      s[2] = (short)f2bf(f0.z); s[3] = (short)f2bf(f0.w);
      s[4] = (short)f2bf(f1.x); s[5] = (short)f2bf(f1.y);
      s[6] = (short)f2bf(f1.z); s[7] = (short)f2bf(f1.w);
      afr[ti][ks] = s;
    }
  }
  for (int nt = 0; nt < 16; ++nt) {
    const int n = nt * 16 + m16;
    const unsigned short* wr = Wbf + n * 256 + kg * 8;
    f32x4 acc0 = {0.f, 0.f, 0.f, 0.f}, acc1 = {0.f, 0.f, 0.f, 0.f};
    for (int ks = 0; ks < 8; ++ks) {
      short8 b = *(const short8*)(wr + ks * 32);
      acc0 = __builtin_amdgcn_mfma_f32_16x16x32_bf16(afr[0][ks], b, acc0, 0, 0, 0);
      acc1 = __builtin_amdgcn_mfma_f32_16x16x32_bf16(afr[1][ks], b, acc1, 0, 0, 0);
    }
    for (int r = 0; r < 4; ++r) {
      Cout[(tile0 * 16 + kg * 4 + r) * 256 + n]       = acc0[r];
      Cout[((tile0 + 1) * 16 + kg * 4 + r) * 256 + n] = acc1[r];
    }
  }
}

// ---- kernel 2: sequential scan, INT8. 64 blocks x 1 batch row,
// 4 waves x 64 cols (one wave per SIMD). Per CU-step: 16 ds_read_b128
// (halved vs 8-wave) + 64 mfma_i32_16x16x64_i8 (4 indep depth-4 chains/wave).
// h: 256 int8 in klin order, double-buffered. Epilogue: 1 ds_write_b32 +
// 1 global 8B store per data lane.
__global__ __launch_bounds__(256, 1) void rnn_scan(
    const float* __restrict__ xp, const char* __restrict__ Wq,
    const float* __restrict__ h0, unsigned short* __restrict__ hs) {
  __shared__ __align__(16) char hq[2][256];
  const int tid = threadIdx.x, w = tid >> 6, l = tid & 63;
  const int b = blockIdx.x;           // one batch row per block
  const int m16 = l & 15, kg = l >> 4;

  // W_hid i8 B-fragments resident: wave owns orig cols [w*64, w*64+64)
  i32x4 bq[4][4];
  for (int nt = 0; nt < 4; ++nt) {
    const char* wr = Wq + (w * 64 + nt * 16 + m16) * 256 + kg * 16;
    for (int ks = 0; ks < 4; ++ks) bq[nt][ks] = *(const i32x4*)(wr + ks * 64);
  }

  {                                   // h0 ingest (klin order), quantized
    float v = fminf(fmaxf(h0[b * 256 + p2c(tid)], -1.f), 1.f) * HSCALE;
    hq[0][tid] = (char)(int)__builtin_rintf(v);
  }
  __syncthreads();

  const char* rda = &hq[0][0] + kg * 16;                // + CUR*256 + ks*64 (imm)
  const float* xpb = xp + (long)b * 256 + w * 64 + m16; // + t*NBDH + nt*16
  uint2* hsw = (uint2*)(hs + (long)b * 256 + w * 64 + 4 * m16);  // + t*4096 (uint2)
  unsigned* ldw0 = (unsigned*)&hq[0][w * 64 + 4 * m16];
  unsigned* ldw1 = (unsigned*)&hq[1][w * 64 + 4 * m16];

  // 4-deep xp prefetch rotation (loads only on data-carrying lanes)
  float xv0[4], xv1[4], xv2[4], xv3[4];
  if (l < 16) {
    for (int nt = 0; nt < 4; ++nt) {
      xv0[nt] = xpb[nt * 16];
      xv1[nt] = xpb[1L * NBDH + nt * 16];
      xv2[nt] = xpb[2L * NBDH + nt * 16];
      xv3[nt] = xpb[3L * NBDH + nt * 16];
    }
  }

#define MI8(A, B, C) __builtin_amdgcn_mfma_i32_16x16x64_i8(A, B, C, 0, 0, 0)
#define RNN_STEP(T, CUR, XV, PF)                                              \
  {                                                                           \
    const char* ap = rda + (CUR) * 256;                                       \
    i32x4 a0 = *(const i32x4*)(ap);                                           \
    i32x4 a1 = *(const i32x4*)(ap + 64);                                      \
    i32x4 a2 = *(const i32x4*)(ap + 128);                                     \
    i32x4 a3 = *(const i32x4*)(ap + 192);                                     \
    float xq0 = XV[0], xq1 = XV[1], xq2 = XV[2], xq3 = XV[3];                 \
    i32x4 c0 = {0,0,0,0}, c1 = {0,0,0,0}, c2 = {0,0,0,0}, c3 = {0,0,0,0};     \
    if ((PF) && l < 16) {             /* prefetch t+4 (XV consumed above) */  \
      const float* q = xpb + (long)((T) + 4) * NBDH;                          \
      XV[0] = q[0]; XV[1] = q[16]; XV[2] = q[32]; XV[3] = q[48];              \
    }                                                                         \
    c0 = MI8(a0, bq[0][0], c0); c1 = MI8(a0, bq[1][0], c1);                   \
    c2 = MI8(a0, bq[2][0], c2); c3 = MI8(a0, bq[3][0], c3);                   \
    c0 = MI8(a1, bq[0][1], c0); c1 = MI8(a1, bq[1][1], c1);                   \
    c2 = MI8(a1, bq[2][1], c2); c3 = MI8(a1, bq[3][1], c3);                   \
    c0 = MI8(a2, bq[0][2], c0); c1 = MI8(a2, bq[1][2], c1);                   \
    c2 = MI8(a2, bq[2][2], c2); c3 = MI8(a2, bq[3][2], c3);                   \
    c0 = MI8(a3, bq[0][3], c0); c1 = MI8(a3, bq[1][3], c1);                   \
    c2 = MI8(a3, bq[2][3], c2); c3 = MI8(a3, bq[3][3], c3);                   \
    float z0 = (float)c0[0] * INVSC + xq0;                                    \
    float z1 = (float)c1[0] * INVSC + xq1;                                    \
    float z2 = (float)c2[0] * INVSC + xq2;                                    \
    float z3 = (float)c3[0] * INVSC + xq3;                                    \
    float t0 = fast_tanh(z0), t1 = fast_tanh(z1);                             \
    float t2 = fast_tanh(z2), t3 = fast_tanh(z3);                             \
    unsigned pk0, pk1;                                                        \
    asm("v_cvt_pk_bf16_f32 %0, %1, %2" : "=v"(pk0) : "v"(t0), "v"(t1));       \
    asm("v_cvt_pk_bf16_f32 %0, %1, %2" : "=v"(pk1) : "v"(t2), "v"(t3));       \
    int q0 = (int)__builtin_rintf(t0 * HSCALE);                               \
    int q1 = (int)__builtin_rintf(t1 * HSCALE);                               \
    int q2 = (int)__builtin_rintf(t2 * HSCALE);                               \
    int q3 = (int)__builtin_rintf(t3 * HSCALE);                               \
    unsigned uq = (q0 & 0xFF) | ((q1 & 0xFF) << 8) |                          \
                  ((q2 & 0xFF) << 16) | ((unsigned)(q3 & 0xFF) << 24);        \
    if (l < 16) {                                                             \
      *((CUR) ? ldw0 : ldw1) = uq;                                            \
      uint2 st; st.x = pk0; st.y = pk1;                                       \
      hsw[(long)(T) * 4096] = st;                                             \
    }                                                                         \
    asm volatile("s_waitcnt lgkmcnt(0)" ::: "memory");  /* LDS drain only */  \
    __builtin_amdgcn_s_barrier();                                             \
    __builtin_amdgcn_sched_barrier(0);                                        \
  }

#pragma unroll 1
  for (int t = 0; t < TSTEPS - 4; t += 4) {
    RNN_STEP(t, 0, xv0, true);
    RNN_STEP(t + 1, 1, xv1, true);
    RNN_STEP(t + 2, 0, xv2, true);
    RNN_STEP(t + 3, 1, xv3, true);
  }
  RNN_STEP(TSTEPS - 4, 0, xv0, false);
  RNN_STEP(TSTEPS - 3, 1, xv1, false);
  RNN_STEP(TSTEPS - 2, 0, xv2, false);
  RNN_STEP(TSTEPS - 1, 1, xv3, false);
#undef RNN_STEP
#undef MI8
}

// ---- kernel 3: output GEMM, ys[M,256] = hs[M,klin] @ Wout_p[n,klin]^T (bf16 A)
__global__ __launch_bounds__(256) void gemm_out(
    const unsigned short* __restrict__ Abf, const unsigned short* __restrict__ Wbf,
    float* __restrict__ Cout) {
  const int w = threadIdx.x >> 6, l = threadIdx.x & 63;
  const int m16 = l & 15, kg = l >> 4;
  const long tile0 = ((long)blockIdx.x * 4 + w) * 2;

  short8 afr[2][8];
  for (int ti = 0; ti < 2; ++ti) {
    const unsigned short* ar = Abf + ((tile0 + ti) * 16 + m16) * 256 + kg * 8;
    for (int ks = 0; ks < 8; ++ks) afr[ti][ks] = *(const short8*)(ar + ks * 32);
  }
  for (int nt = 0; nt < 16; ++nt) {
    const int n = nt * 16 + m16;
    const unsigned short* wr = Wbf + n * 256 + kg * 8;
    f32x4 acc0 = {0.f, 0.f, 0.f, 0.f}, acc1 = {0.f, 0.f, 0.f, 0.f};
    for (int ks = 0; ks < 8; ++ks) {
      short8 b = *(const short8*)(wr + ks * 32);
      acc0 = __builtin_amdgcn_mfma_f32_16x16x32_bf16(afr[0][ks], b, acc0, 0, 0, 0);
      acc1 = __builtin_amdgcn_mfma_f32_16x16x32_bf16(afr[1][ks], b, acc1, 0, 0, 0);
    }
    for (int r = 0; r < 4; ++r) {
      Cout[(tile0 * 16 + kg * 4 + r) * 256 + n]       = acc0[r];
      Cout[((tile0 + 1) * 16 + kg * 4 + r) * 256 + n] = acc1[r];
    }
  }
}

// ---- kernel 4: h_last[b][c] = f32(hs[T-1][b][klin]), un-permuting columns
__global__ void hlast_k(const unsigned short* __restrict__ hs, float* __restrict__ hlast) {
  int i = blockIdx.x * 1024 + threadIdx.x;          // 16 blocks x 1024 = 16384
  int b = i >> 8, p = i & 255;
  unsigned u = (unsigned)hs[(long)(TSTEPS - 1) * NBDH + b * 256 + p] << 16;
  union { unsigned u; float f; } v; v.u = u;
  hlast[b * 256 + p2c(p)] = v.f;
}

extern "C" void kernel_launch(void* const* d_in, const int* in_sizes, int n_in,
                              void* d_out, int out_size, void* d_ws, size_t ws_size,
                              hipStream_t stream) {
  const float* x    = (const float*)d_in[0];
  const float* h0   = (const float*)d_in[1];
  const float* Win  = (const float*)d_in[2];
  const float* Whid = (const float*)d_in[3];
  const float* Wout = (const float*)d_in[4];
  float* ys    = (float*)d_out;
  float* hlast = ys + (long)TSTEPS * NB * 256;

  // d_ws: [bf16 W_in | bf16 Wout_p | i8 Whid_q | f32 xp (128MB) | bf16 hs klin (64MB)]
  unsigned short* wbf     = (unsigned short*)d_ws;               // 2x65536 u16
  unsigned short* wbf_in  = wbf;
  unsigned short* wbf_out = wbf + 65536;
  char* wq_hid = (char*)d_ws + 262144;                           // 65536 B
  float* xproj = (float*)((char*)d_ws + 393216);
  unsigned short* hsbuf =
      (unsigned short*)((char*)d_ws + 393216 + (size_t)TSTEPS * NB * 256 * 4);

  cvt_w<<<dim3(768), dim3(256), 0, stream>>>(Win, Whid, Wout, wbf, wq_hid);
  gemm_in<<<dim3(1024), dim3(256), 0, stream>>>(x, wbf_in, xproj);
  rnn_scan<<<dim3(64), dim3(256), 0, stream>>>(xproj, wq_hid, h0, hsbuf);
  gemm_out<<<dim3(1024), dim3(256), 0, stream>>>(hsbuf, wbf_out, ys);
  hlast_k<<<dim3(16), dim3(1024), 0, stream>>>(hsbuf, hlast);
}

// Round 12
// 954.939 us; speedup vs baseline: 1.0311x; 1.0311x over previous
//
#include <hip/hip_runtime.h>
#include <hip/hip_bf16.h>

#define TSTEPS 2048
#define NB 64
#define DH 256
#define NBDH (NB * DH)

typedef __attribute__((ext_vector_type(8))) short short8;
typedef __attribute__((ext_vector_type(4))) float f32x4;
typedef __attribute__((ext_vector_type(4))) int i32x4;

#define WSCALE 2032.0f
#define HSCALE 127.0f
#define INVSC (1.0f / (2032.0f * 127.0f))

__device__ __forceinline__ unsigned short f2bf(float f) {
  union { float f; unsigned u; } v; v.f = f;
  unsigned u = v.u;
  u += 0x7FFFu + ((u >> 16) & 1u);   // round-to-nearest-even
  return (unsigned short)(u >> 16);
}

__device__ __forceinline__ float fast_tanh(float x) {
  // tanh(x) = 1 - 2/(e^{2x}+1); saturates correctly at +/-1
  float e = __builtin_amdgcn_exp2f(x * 2.885390081777927f);  // e^{2x}
  return 1.0f - 2.0f * __builtin_amdgcn_rcpf(e + 1.0f);
}

// klin pairing permutation (r3/r10-verified): stored pos p <-> orig col c
// p = g*32 + 2*j + half  <->  c = g*32 + half*16 + j
__device__ __forceinline__ int p2c(int p) {
  int q = p & 31;
  return (p & ~31) | ((q & 1) << 4) | (q >> 1);
}

// ---- kernel 0: W_in -> bf16 (unpermuted); W_hid, W_out -> int8 k-permuted
// (klin), scale 2032 (both are U(-1/16, 1/16)).
__global__ void cvt_w(const float* __restrict__ win, const float* __restrict__ whid,
                      const float* __restrict__ wout, unsigned short* __restrict__ wbf,
                      char* __restrict__ wq) {
  int i = blockIdx.x * 256 + threadIdx.x;  // 0 .. 3*65536-1
  int mat = i >> 16, idx = i & 65535;
  int n = idx >> 8, klin = idx & 255;
  if (mat == 0) {
    wbf[idx] = f2bf(win[idx]);
  } else {
    const float* m = (mat == 1) ? whid : wout;
    float v = m[n * 256 + p2c(klin)] * WSCALE;
    int q = (int)__builtin_rintf(fminf(fmaxf(v, -127.f), 127.f));
    wq[(mat - 1) * 65536 + idx] = (char)q;
  }
}

// ---- kernel 1: input GEMM  xp[M,256] = x[M,256] @ W_in^T  (f32 out)
__global__ __launch_bounds__(256) void gemm_in(
    const float* __restrict__ x, const unsigned short* __restrict__ Wbf,
    float* __restrict__ Cout) {
  const int w = threadIdx.x >> 6, l = threadIdx.x & 63;
  const int m16 = l & 15, kg = l >> 4;
  const long tile0 = ((long)blockIdx.x * 4 + w) * 2;

  short8 afr[2][8];
  for (int ti = 0; ti < 2; ++ti) {
    const float* ar = x + ((tile0 + ti) * 16 + m16) * 256 + kg * 8;
    for (int ks = 0; ks < 8; ++ks) {
      float4 f0 = *(const float4*)(ar + ks * 32);
      float4 f1 = *(const float4*)(ar + ks * 32 + 4);
      short8 s;
      s[0] = (short)f2bf(f0.x); s[1] = (short)f2bf(f0.y);
      s[2] = (short)f2bf(f0.z); s[3] = (short)f2bf(f0.w);
      s[4] = (short)f2bf(f1.x); s[5] = (short)f2bf(f1.y);
      s[6] = (short)f2bf(f1.z); s[7] = (short)f2bf(f1.w);
      afr[ti][ks] = s;
    }
  }
  for (int nt = 0; nt < 16; ++nt) {
    const int n = nt * 16 + m16;
    const unsigned short* wr = Wbf + n * 256 + kg * 8;
    f32x4 acc0 = {0.f, 0.f, 0.f, 0.f}, acc1 = {0.f, 0.f, 0.f, 0.f};
    for (int ks = 0; ks < 8; ++ks) {
      short8 b = *(const short8*)(wr + ks * 32);
      acc0 = __builtin_amdgcn_mfma_f32_16x16x32_bf16(afr[0][ks], b, acc0, 0, 0, 0);
      acc1 = __builtin_amdgcn_mfma_f32_16x16x32_bf16(afr[1][ks], b, acc1, 0, 0, 0);
    }
    for (int r = 0; r < 4; ++r) {
      Cout[(tile0 * 16 + kg * 4 + r) * 256 + n]       = acc0[r];
      Cout[((tile0 + 1) * 16 + kg * 4 + r) * 256 + n] = acc1[r];
    }
  }
}

// ---- kernel 2: fused scan + output projection, INT8. 64 blocks x 1 row,
// 8 waves x 32 cols (r10 structure, 713us proven). Per step, besides the
// recurrence (8 MFMA), each wave does 8 MORE i8 MFMAs reusing the SAME
// a0..a3 registers against W_out fragments -> ys[t-1] emitted in step t
// (a holds h_{t-1}). Eliminates gemm_out + hs round-trip entirely.
__global__ __launch_bounds__(512, 2) void rnn_scan(
    const float* __restrict__ xp, const char* __restrict__ Wq,
    const float* __restrict__ h0, float* __restrict__ ys,
    float* __restrict__ hlast) {
  __shared__ __align__(16) char hq[2][256];
  const int tid = threadIdx.x, w = tid >> 6, l = tid & 63;
  const int b = blockIdx.x;           // one batch row per block
  const int m16 = l & 15, kg = l >> 4;

  // W_hid (bq) and W_out (by) i8 fragments: wave owns orig cols [w*32, w*32+32)
  i32x4 bq[2][4], by[2][4];
  for (int nt = 0; nt < 2; ++nt) {
    const char* wr = Wq + (w * 32 + nt * 16 + m16) * 256 + kg * 16;
    for (int ks = 0; ks < 4; ++ks) {
      bq[nt][ks] = *(const i32x4*)(wr + ks * 64);
      by[nt][ks] = *(const i32x4*)(wr + 65536 + ks * 64);
    }
  }

  if (tid < 256) {                    // h0 ingest (klin order), quantized
    float v = fminf(fmaxf(h0[b * 256 + p2c(tid)], -1.f), 1.f) * HSCALE;
    hq[0][tid] = (char)(int)__builtin_rintf(v);
  }
  __syncthreads();

  const char* rda = &hq[0][0] + kg * 16;                // + CUR*256 + ks*64 (imm)
  const float* xpb = xp + (long)b * 256 + w * 32 + m16; // + t*NBDH (+16 for nt1)
  float* ysb = ys + (long)b * 256 + w * 32 + l;         // + t*NBDH (+16 for nt1)

  // 4-deep xp prefetch rotation (loads only on data-carrying lanes)
  float xv0[2], xv1[2], xv2[2], xv3[2];
  if (l < 16) {
    xv0[0] = xpb[0];               xv0[1] = xpb[16];
    xv1[0] = xpb[1L * NBDH];       xv1[1] = xpb[1L * NBDH + 16];
    xv2[0] = xpb[2L * NBDH];       xv2[1] = xpb[2L * NBDH + 16];
    xv3[0] = xpb[3L * NBDH];       xv3[1] = xpb[3L * NBDH + 16];
  }

#define MI8(A, B, C) __builtin_amdgcn_mfma_i32_16x16x64_i8(A, B, C, 0, 0, 0)
#define RNN_STEP(T, CUR, XV, PF)                                              \
  {                                                                           \
    const char* ap = rda + (CUR) * 256;                                       \
    i32x4 a0 = *(const i32x4*)(ap);                                           \
    i32x4 a1 = *(const i32x4*)(ap + 64);                                      \
    i32x4 a2 = *(const i32x4*)(ap + 128);                                     \
    i32x4 a3 = *(const i32x4*)(ap + 192);                                     \
    float xq0 = XV[0], xq1 = XV[1];   /* capture THIS step's xp first */      \
    i32x4 c0 = {0, 0, 0, 0}, c1 = {0, 0, 0, 0};                               \
    if ((PF) && l < 16) {             /* prefetch t+4 (XV consumed above) */  \
      const float* q = xpb + (long)((T) + 4) * NBDH;                          \
      XV[0] = q[0]; XV[1] = q[16];                                            \
    }                                                                         \
    c0 = MI8(a0, bq[0][0], c0); c1 = MI8(a0, bq[1][0], c1);                   \
    c0 = MI8(a1, bq[0][1], c0); c1 = MI8(a1, bq[1][1], c1);                   \
    c0 = MI8(a2, bq[0][2], c0); c1 = MI8(a2, bq[1][2], c1);                   \
    c0 = MI8(a3, bq[0][3], c0); c1 = MI8(a3, bq[1][3], c1);                   \
    i32x4 y0 = {0, 0, 0, 0}, y1 = {0, 0, 0, 0};   /* ys[T-1] = h_{T-1}@Wout */\
    y0 = MI8(a0, by[0][0], y0); y1 = MI8(a0, by[1][0], y1);                   \
    y0 = MI8(a1, by[0][1], y0); y1 = MI8(a1, by[1][1], y1);                   \
    y0 = MI8(a2, by[0][2], y0); y1 = MI8(a2, by[1][2], y1);                   \
    y0 = MI8(a3, by[0][3], y0); y1 = MI8(a3, by[1][3], y1);                   \
    float z0 = (float)c0[0] * INVSC + xq0;                                    \
    float z1 = (float)c1[0] * INVSC + xq1;                                    \
    float t0 = fast_tanh(z0), t1 = fast_tanh(z1);                             \
    int q0 = (int)__builtin_rintf(t0 * HSCALE);                               \
    int q1 = (int)__builtin_rintf(t1 * HSCALE);                               \
    unsigned short uq = (unsigned short)((q0 & 0xFF) | ((q1 & 0xFF) << 8));   \
    if (l < 16) {                                                             \
      *(unsigned short*)(&hq[(CUR) ^ 1][w * 32 + 2 * l]) = uq;                \
      if ((T) > 0) {                                                          \
        ysb[(long)((T) - 1) * NBDH]      = (float)y0[0] * INVSC;              \
        ysb[(long)((T) - 1) * NBDH + 16] = (float)y1[0] * INVSC;              \
      }                                                                       \
      if ((T) == TSTEPS - 1) {                                                \
        hlast[b * 256 + w * 32 + l]      = t0;                                \
        hlast[b * 256 + w * 32 + 16 + l] = t1;                                \
      }                                                                       \
    }                                                                         \
    asm volatile("s_waitcnt lgkmcnt(0)" ::: "memory");  /* LDS drain only */  \
    __builtin_amdgcn_s_barrier();                                             \
    __builtin_amdgcn_sched_barrier(0);                                        \
  }

#pragma unroll 1
  for (int t = 0; t < TSTEPS - 4; t += 4) {
    RNN_STEP(t, 0, xv0, true);
    RNN_STEP(t + 1, 1, xv1, true);
    RNN_STEP(t + 2, 0, xv2, true);
    RNN_STEP(t + 3, 1, xv3, true);
  }
  RNN_STEP(TSTEPS - 4, 0, xv0, false);
  RNN_STEP(TSTEPS - 3, 1, xv1, false);
  RNN_STEP(TSTEPS - 2, 0, xv2, false);
  RNN_STEP(TSTEPS - 1, 1, xv3, false);
#undef RNN_STEP

  // final y-pass: ys[T-1] from the last h (step 2047 had CUR=1 -> wrote hq[0])
  {
    const char* ap = rda;             // hq[0]
    i32x4 a0 = *(const i32x4*)(ap);
    i32x4 a1 = *(const i32x4*)(ap + 64);
    i32x4 a2 = *(const i32x4*)(ap + 128);
    i32x4 a3 = *(const i32x4*)(ap + 192);
    i32x4 y0 = {0, 0, 0, 0}, y1 = {0, 0, 0, 0};
    y0 = MI8(a0, by[0][0], y0); y1 = MI8(a0, by[1][0], y1);
    y0 = MI8(a1, by[0][1], y0); y1 = MI8(a1, by[1][1], y1);
    y0 = MI8(a2, by[0][2], y0); y1 = MI8(a2, by[1][2], y1);
    y0 = MI8(a3, by[0][3], y0); y1 = MI8(a3, by[1][3], y1);
    if (l < 16) {
      ysb[(long)(TSTEPS - 1) * NBDH]      = (float)y0[0] * INVSC;
      ysb[(long)(TSTEPS - 1) * NBDH + 16] = (float)y1[0] * INVSC;
    }
  }
#undef MI8
}

extern "C" void kernel_launch(void* const* d_in, const int* in_sizes, int n_in,
                              void* d_out, int out_size, void* d_ws, size_t ws_size,
                              hipStream_t stream) {
  const float* x    = (const float*)d_in[0];
  const float* h0   = (const float*)d_in[1];
  const float* Win  = (const float*)d_in[2];
  const float* Whid = (const float*)d_in[3];
  const float* Wout = (const float*)d_in[4];
  float* ys    = (float*)d_out;
  float* hlast = ys + (long)TSTEPS * NB * 256;

  // d_ws: [bf16 W_in (128KB) | i8 Whid_q + Wout_q (128KB) | f32 xp (128MB)]
  unsigned short* wbf_in = (unsigned short*)d_ws;
  char* wq = (char*)d_ws + 131072;
  float* xproj = (float*)((char*)d_ws + 262144);

  cvt_w<<<dim3(768), dim3(256), 0, stream>>>(Win, Whid, Wout, wbf_in, wq);
  gemm_in<<<dim3(1024), dim3(256), 0, stream>>>(x, wbf_in, xproj);
  rnn_scan<<<dim3(64), dim3(512), 0, stream>>>(xproj, wq, h0, ys, hlast);
}